// Round 3
// baseline (511.305 us; speedup 1.0000x reference)
//
#include <hip/hip_runtime.h>
#include <math.h>

#define N_NODES 50000
#define N_EDGES 800000
#define TOT_E   850000          // N_EDGES + N_NODES self loops
#define IN_DIM  512
#define HID_DIM 64
#define OUT_DIM 40
#define H_ELEMS 3200000         // N_NODES*HID_DIM

// ---------------- Threefry-2x32, JAX-exact, key = (0, 42) ----------------
__device__ __forceinline__ unsigned rotl32(unsigned v, int n) {
  return (v << n) | (v >> (32 - n));
}

__device__ __forceinline__ void threefry2x32_0_42(unsigned x0, unsigned x1,
                                                  unsigned &o0, unsigned &o1) {
  const unsigned ks0 = 0u;
  const unsigned ks1 = 42u;
  const unsigned ks2 = 0u ^ 42u ^ 0x1BD11BDAu;
  x0 += ks0; x1 += ks1;
  // group 1: rot 13,15,26,6
  x0 += x1; x1 = rotl32(x1, 13); x1 ^= x0;
  x0 += x1; x1 = rotl32(x1, 15); x1 ^= x0;
  x0 += x1; x1 = rotl32(x1, 26); x1 ^= x0;
  x0 += x1; x1 = rotl32(x1,  6); x1 ^= x0;
  x0 += ks1; x1 += ks2 + 1u;
  // group 2: rot 17,29,16,24
  x0 += x1; x1 = rotl32(x1, 17); x1 ^= x0;
  x0 += x1; x1 = rotl32(x1, 29); x1 ^= x0;
  x0 += x1; x1 = rotl32(x1, 16); x1 ^= x0;
  x0 += x1; x1 = rotl32(x1, 24); x1 ^= x0;
  x0 += ks2; x1 += ks0 + 2u;
  // group 3: rot 13,15,26,6
  x0 += x1; x1 = rotl32(x1, 13); x1 ^= x0;
  x0 += x1; x1 = rotl32(x1, 15); x1 ^= x0;
  x0 += x1; x1 = rotl32(x1, 26); x1 ^= x0;
  x0 += x1; x1 = rotl32(x1,  6); x1 ^= x0;
  x0 += ks0; x1 += ks1 + 3u;
  // group 4: rot 17,29,16,24
  x0 += x1; x1 = rotl32(x1, 17); x1 ^= x0;
  x0 += x1; x1 = rotl32(x1, 29); x1 ^= x0;
  x0 += x1; x1 = rotl32(x1, 16); x1 ^= x0;
  x0 += x1; x1 = rotl32(x1, 24); x1 ^= x0;
  x0 += ks1; x1 += ks2 + 4u;
  // group 5: rot 13,15,26,6
  x0 += x1; x1 = rotl32(x1, 13); x1 ^= x0;
  x0 += x1; x1 = rotl32(x1, 15); x1 ^= x0;
  x0 += x1; x1 = rotl32(x1, 26); x1 ^= x0;
  x0 += x1; x1 = rotl32(x1,  6); x1 ^= x0;
  x0 += ks2; x1 += ks0 + 5u;
  o0 = x0; o1 = x1;
}

// ---------------- degree / normalization ----------------
__global__ void k_init_deg(float* __restrict__ deg) {
  int i = blockIdx.x * 256 + threadIdx.x;
  if (i < N_NODES) deg[i] = 1.0f;     // self-loop
}

__global__ void k_deg(const int* __restrict__ dst, float* __restrict__ deg) {
  int e = blockIdx.x * 256 + threadIdx.x;
  if (e < N_EDGES) atomicAdd(&deg[dst[e]], 1.0f);
}

__global__ void k_rsqrt(float* __restrict__ deg) {
  int i = blockIdx.x * 256 + threadIdx.x;
  if (i < N_NODES) deg[i] = 1.0f / sqrtf(deg[i]);
}

// ---------------- weight repack ----------------
__global__ void k_wprep(const float* __restrict__ W1, const float* __restrict__ W2,
                        float* __restrict__ Wp1, float* __restrict__ Wp2) {
  int i = blockIdx.x * 256 + threadIdx.x;
  if (i < IN_DIM * HID_DIM) {
    int k = i >> 6, c = i & 63;
    Wp1[((k >> 2) << 8) + (c << 2) + (k & 3)] = W1[i];
  }
  if (i < HID_DIM * OUT_DIM) {
    int k = i / OUT_DIM, c = i - k * OUT_DIM;
    Wp2[(k >> 2) * (OUT_DIM * 4) + (c << 2) + (k & 3)] = W2[i];
  }
}

// ---------------- GEMM1: ht1 = x @ W1   [50000x512]@[512x64] ----------------
__global__ __launch_bounds__(256) void k_gemm1(const float* __restrict__ x,
                                               const float* __restrict__ Wp1,
                                               float* __restrict__ ht1) {
  const int lane = threadIdx.x & 63;
  const int wave = threadIdx.x >> 6;                          // 0..3
  const int cg = __builtin_amdgcn_readfirstlane(wave);        // col group, uniform
  const int row = blockIdx.x * 64 + lane;
  const bool valid = row < N_NODES;
  const float4* __restrict__ xrow =
      (const float4*)(x + (size_t)(valid ? row : 0) * IN_DIM);

  float acc[16];
#pragma unroll
  for (int i = 0; i < 16; ++i) acc[i] = 0.0f;

  for (int k0 = 0; k0 < IN_DIM; k0 += 4) {
    float4 x4 = xrow[k0 >> 2];
    const float4* __restrict__ wv = (const float4*)(Wp1 + (k0 >> 2) * 256 + cg * 64);
#pragma unroll
    for (int c = 0; c < 16; ++c) {
      float4 w = wv[c];
      acc[c] += x4.x * w.x;
      acc[c] += x4.y * w.y;
      acc[c] += x4.z * w.z;
      acc[c] += x4.w * w.w;
    }
  }
  if (valid) {
    float* __restrict__ o = ht1 + (size_t)row * HID_DIM + cg * 16;
#pragma unroll
    for (int c = 0; c < 16; ++c) o[c] = acc[c];
  }
}

// ---------------- scatter 1: agg[dst] += dis[s]*dis[d]*ht1[src]  (64 feats) ----
__global__ __launch_bounds__(256) void k_scatter1(const int* __restrict__ ei,
                                                  const float* __restrict__ dis,
                                                  const float* __restrict__ ht1,
                                                  float* __restrict__ agg) {
  int e = blockIdx.x * 4 + (threadIdx.x >> 6);
  int lane = threadIdx.x & 63;
  if (e >= TOT_E) return;
  int s, d;
  if (e < N_EDGES) { s = ei[e]; d = ei[N_EDGES + e]; }
  else             { s = e - N_EDGES; d = s; }
  float norm = dis[s] * dis[d];
  float v = ht1[(size_t)s * HID_DIM + lane] * norm;
  atomicAdd(&agg[(size_t)d * HID_DIM + lane], v);
}

// ---------------- bias1 + relu + dropout (partitionable threefry, XOR fold) --
// JAX partitionable: counters from iota_2x32_shape -> (hi=0, lo=t) for t<2^32;
// for 32-bit draws the combine is bits = out0 ^ out1. keep <=> !(bits >> 31).
__global__ void k_postproc(float* __restrict__ h, const float* __restrict__ b1) {
  int t = blockIdx.x * 256 + threadIdx.x;
  if (t >= H_ELEMS) return;
  unsigned o0, o1;
  threefry2x32_0_42(0u, (unsigned)t, o0, o1);
  unsigned bits = o0 ^ o1;
  float v = h[t] + b1[t & 63];
  v = fmaxf(v, 0.0f);
  v = (bits & 0x80000000u) ? 0.0f : v * 2.0f;
  h[t] = v;
}

// ---------------- GEMM2: ht2 = h @ W2   [50000x64]@[64x40] -------------------
__global__ __launch_bounds__(256) void k_gemm2(const float* __restrict__ h,
                                               const float* __restrict__ Wp2,
                                               float* __restrict__ ht2) {
  const int lane = threadIdx.x & 63;
  const int wave = threadIdx.x >> 6;                       // 0..3
  const int cg = __builtin_amdgcn_readfirstlane(wave & 1); // 0/1: cols 0..19 / 20..39
  const int rb = wave >> 1;                                // 0/1
  const int row = blockIdx.x * 128 + rb * 64 + lane;
  const bool valid = row < N_NODES;
  const float4* __restrict__ hrow =
      (const float4*)(h + (size_t)(valid ? row : 0) * HID_DIM);

  float acc[20];
#pragma unroll
  for (int i = 0; i < 20; ++i) acc[i] = 0.0f;

  for (int k0 = 0; k0 < HID_DIM; k0 += 4) {
    float4 x4 = hrow[k0 >> 2];
    const float4* __restrict__ wv = (const float4*)(Wp2 + (k0 >> 2) * 160 + cg * 80);
#pragma unroll
    for (int c = 0; c < 20; ++c) {
      float4 w = wv[c];
      acc[c] += x4.x * w.x;
      acc[c] += x4.y * w.y;
      acc[c] += x4.z * w.z;
      acc[c] += x4.w * w.w;
    }
  }
  if (valid) {
    float* __restrict__ o = ht2 + (size_t)row * OUT_DIM + cg * 20;
#pragma unroll
    for (int c = 0; c < 20; ++c) o[c] = acc[c];
  }
}

// ---------------- scatter 2: out[dst] += norm*ht2[src]  (40 feats) -----------
__global__ __launch_bounds__(256) void k_scatter2(const int* __restrict__ ei,
                                                  const float* __restrict__ dis,
                                                  const float* __restrict__ ht2,
                                                  float* __restrict__ out) {
  int e = blockIdx.x * 4 + (threadIdx.x >> 6);
  int lane = threadIdx.x & 63;
  if (e >= TOT_E || lane >= OUT_DIM) return;
  int s, d;
  if (e < N_EDGES) { s = ei[e]; d = ei[N_EDGES + e]; }
  else             { s = e - N_EDGES; d = s; }
  float norm = dis[s] * dis[d];
  float v = ht2[(size_t)s * OUT_DIM + lane] * norm;
  atomicAdd(&out[(size_t)d * OUT_DIM + lane], v);
}

// ---------------- + b2, log_softmax rows, in place ---------------------------
__global__ void k_logsoftmax(float* __restrict__ out, const float* __restrict__ b2) {
  int r = blockIdx.x * 256 + threadIdx.x;
  if (r >= N_NODES) return;
  float* __restrict__ p = out + (size_t)r * OUT_DIM;
  float v[OUT_DIM];
  float m = -INFINITY;
#pragma unroll
  for (int c = 0; c < OUT_DIM; ++c) {
    v[c] = p[c] + b2[c];
    m = fmaxf(m, v[c]);
  }
  float s = 0.0f;
#pragma unroll
  for (int c = 0; c < OUT_DIM; ++c) s += expf(v[c] - m);
  float ls = logf(s) + m;
#pragma unroll
  for (int c = 0; c < OUT_DIM; ++c) p[c] = v[c] - ls;
}

// ---------------- launch ----------------
extern "C" void kernel_launch(void* const* d_in, const int* in_sizes, int n_in,
                              void* d_out, int out_size, void* d_ws, size_t ws_size,
                              hipStream_t stream) {
  const float* x  = (const float*)d_in[0];
  const int*   ei = (const int*)  d_in[1];
  const float* W1 = (const float*)d_in[2];
  const float* b1 = (const float*)d_in[3];
  const float* W2 = (const float*)d_in[4];
  const float* b2 = (const float*)d_in[5];
  float* out = (float*)d_out;
  float* ws  = (float*)d_ws;

  // ws layout (floats)
  float* deg = ws;                          // 50000 (becomes dis in place)
  float* ht  = ws + 51200;                  // 3.2M  (ht1, then reused as ht2)
  float* agg = ws + 51200 + 3200000;        // 3.2M  (agg1 / dropped h)
  float* Wp1 = agg + 3200000;               // 32768
  float* Wp2 = Wp1 + 32768;                 // 2560

  hipMemsetAsync(agg, 0, (size_t)N_NODES * HID_DIM * sizeof(float), stream);
  hipMemsetAsync(out, 0, (size_t)N_NODES * OUT_DIM * sizeof(float), stream);

  k_init_deg<<<196, 256, 0, stream>>>(deg);
  k_deg<<<3125, 256, 0, stream>>>(ei + N_EDGES, deg);
  k_rsqrt<<<196, 256, 0, stream>>>(deg);
  k_wprep<<<128, 256, 0, stream>>>(W1, W2, Wp1, Wp2);

  k_gemm1<<<782, 256, 0, stream>>>(x, Wp1, ht);
  k_scatter1<<<212500, 256, 0, stream>>>(ei, deg, ht, agg);
  k_postproc<<<12500, 256, 0, stream>>>(agg, b1);
  k_gemm2<<<391, 256, 0, stream>>>(agg, Wp2, ht);
  k_scatter2<<<212500, 256, 0, stream>>>(ei, deg, ht, out);
  k_logsoftmax<<<196, 256, 0, stream>>>(out, b2);
}

// Round 4
// 329.860 us; speedup vs baseline: 1.5501x; 1.5501x over previous
//
#include <hip/hip_runtime.h>
#include <math.h>
#include <float.h>

#define N_NODES 50000
#define N_EDGES 800000
#define TOT_E   850000          // N_EDGES + N_NODES self loops
#define IN_DIM  512
#define HID_DIM 64
#define OUT_DIM 40

// ---------------- Threefry-2x32, JAX-exact, key = (0, 42) ----------------
__device__ __forceinline__ unsigned rotl32(unsigned v, int n) {
  return (v << n) | (v >> (32 - n));
}

__device__ __forceinline__ void threefry2x32_0_42(unsigned x0, unsigned x1,
                                                  unsigned &o0, unsigned &o1) {
  const unsigned ks0 = 0u;
  const unsigned ks1 = 42u;
  const unsigned ks2 = 0u ^ 42u ^ 0x1BD11BDAu;
  x0 += ks0; x1 += ks1;
  x0 += x1; x1 = rotl32(x1, 13); x1 ^= x0;
  x0 += x1; x1 = rotl32(x1, 15); x1 ^= x0;
  x0 += x1; x1 = rotl32(x1, 26); x1 ^= x0;
  x0 += x1; x1 = rotl32(x1,  6); x1 ^= x0;
  x0 += ks1; x1 += ks2 + 1u;
  x0 += x1; x1 = rotl32(x1, 17); x1 ^= x0;
  x0 += x1; x1 = rotl32(x1, 29); x1 ^= x0;
  x0 += x1; x1 = rotl32(x1, 16); x1 ^= x0;
  x0 += x1; x1 = rotl32(x1, 24); x1 ^= x0;
  x0 += ks2; x1 += ks0 + 2u;
  x0 += x1; x1 = rotl32(x1, 13); x1 ^= x0;
  x0 += x1; x1 = rotl32(x1, 15); x1 ^= x0;
  x0 += x1; x1 = rotl32(x1, 26); x1 ^= x0;
  x0 += x1; x1 = rotl32(x1,  6); x1 ^= x0;
  x0 += ks0; x1 += ks1 + 3u;
  x0 += x1; x1 = rotl32(x1, 17); x1 ^= x0;
  x0 += x1; x1 = rotl32(x1, 29); x1 ^= x0;
  x0 += x1; x1 = rotl32(x1, 16); x1 ^= x0;
  x0 += x1; x1 = rotl32(x1, 24); x1 ^= x0;
  x0 += ks1; x1 += ks2 + 4u;
  x0 += x1; x1 = rotl32(x1, 13); x1 ^= x0;
  x0 += x1; x1 = rotl32(x1, 15); x1 ^= x0;
  x0 += x1; x1 = rotl32(x1, 26); x1 ^= x0;
  x0 += x1; x1 = rotl32(x1,  6); x1 ^= x0;
  x0 += ks2; x1 += ks0 + 5u;
  o0 = x0; o1 = x1;
}

// ---------------- CSR build ----------------
__global__ void k_count(const int* __restrict__ dst, int* __restrict__ counts) {
  int e = blockIdx.x * 256 + threadIdx.x;
  if (e < N_EDGES) atomicAdd(&counts[dst[e]], 1);
}

// inclusive LDS scan of (counts[idx]+1) per 1024-block; incl -> offsets (temp)
__global__ __launch_bounds__(1024) void k_scan1(const int* __restrict__ counts,
                                                int* __restrict__ offsets,
                                                int* __restrict__ bsums) {
  __shared__ int sm[1024];
  int tid = threadIdx.x;
  int idx = blockIdx.x * 1024 + tid;
  int val = (idx < N_NODES) ? counts[idx] + 1 : 0;
  sm[tid] = val;
  __syncthreads();
  for (int off = 1; off < 1024; off <<= 1) {
    int t = (tid >= off) ? sm[tid - off] : 0;
    __syncthreads();
    sm[tid] += t;
    __syncthreads();
  }
  if (idx < N_NODES) offsets[idx] = sm[tid];
  if (tid == 1023) bsums[blockIdx.x] = sm[1023];
}

// exclusive scan of 49 block sums (one wave)
__global__ void k_scan2(const int* __restrict__ bsums, int* __restrict__ bexcl) {
  int lane = threadIdx.x;
  int orig = (lane < 49) ? bsums[lane] : 0;
  int v = orig;
  for (int off = 1; off < 64; off <<= 1) {
    int u = __shfl_up(v, off, 64);
    if (lane >= off) v += u;
  }
  if (lane < 64) bexcl[lane] = v - orig;
}

// finalize: exclusive offsets, cursor, dis, self-loop placement
__global__ __launch_bounds__(1024) void k_scan3(const int* __restrict__ counts,
                                                int* __restrict__ offsets,
                                                int* __restrict__ cursor,
                                                float* __restrict__ dis,
                                                int* __restrict__ elist,
                                                const int* __restrict__ bexcl) {
  int idx = blockIdx.x * 1024 + threadIdx.x;
  if (idx >= N_NODES) return;
  int val = counts[idx] + 1;
  int incl = offsets[idx] + bexcl[blockIdx.x];
  int excl = incl - val;
  offsets[idx] = excl;
  cursor[idx] = excl;
  dis[idx] = rsqrtf((float)val);
  elist[incl - 1] = idx;                    // self-loop in last slot
  if (idx == N_NODES - 1) offsets[N_NODES] = incl;  // == TOT_E
}

__global__ void k_fill(const int* __restrict__ ei, int* __restrict__ cursor,
                       int* __restrict__ elist) {
  int e = blockIdx.x * 256 + threadIdx.x;
  if (e >= N_EDGES) return;
  int s = ei[e], d = ei[N_EDGES + e];
  int pos = atomicAdd(&cursor[d], 1);
  elist[pos] = s;
}

// ---------------- weight repack ----------------
__global__ void k_wprep(const float* __restrict__ W1, const float* __restrict__ W2,
                        float* __restrict__ Wp1, float* __restrict__ Wp2) {
  int i = blockIdx.x * 256 + threadIdx.x;
  if (i < IN_DIM * HID_DIM) {
    int k = i >> 6, c = i & 63;
    Wp1[((k >> 2) << 8) + (c << 2) + (k & 3)] = W1[i];
  }
  if (i < HID_DIM * OUT_DIM) {
    int k = i / OUT_DIM, c = i - k * OUT_DIM;
    Wp2[(k >> 2) * (OUT_DIM * 4) + (c << 2) + (k & 3)] = W2[i];
  }
}

// ---------------- GEMM1: ht1s = dis[row] * (x @ W1) ----------------
__global__ __launch_bounds__(256) void k_gemm1(const float* __restrict__ x,
                                               const float* __restrict__ Wp1,
                                               const float* __restrict__ dis,
                                               float* __restrict__ ht1s) {
  const int lane = threadIdx.x & 63;
  const int wave = threadIdx.x >> 6;
  const int cg = __builtin_amdgcn_readfirstlane(wave);
  const int row = blockIdx.x * 64 + lane;
  const bool valid = row < N_NODES;
  const float4* __restrict__ xrow =
      (const float4*)(x + (size_t)(valid ? row : 0) * IN_DIM);

  float acc[16];
#pragma unroll
  for (int i = 0; i < 16; ++i) acc[i] = 0.0f;

  for (int k0 = 0; k0 < IN_DIM; k0 += 4) {
    float4 x4 = xrow[k0 >> 2];
    const float4* __restrict__ wv = (const float4*)(Wp1 + (k0 >> 2) * 256 + cg * 64);
#pragma unroll
    for (int c = 0; c < 16; ++c) {
      float4 w = wv[c];
      acc[c] += x4.x * w.x;
      acc[c] += x4.y * w.y;
      acc[c] += x4.z * w.z;
      acc[c] += x4.w * w.w;
    }
  }
  if (valid) {
    float dr = dis[row];
    float* __restrict__ o = ht1s + (size_t)row * HID_DIM + cg * 16;
#pragma unroll
    for (int c = 0; c < 16; ++c) o[c] = acc[c] * dr;
  }
}

// ---------------- agg1: h[d] = dropout(relu(dis[d]*sum ht1s[src] + b1)) -----
// wave per node: 4 edge-groups x 16 lanes x float4
__global__ __launch_bounds__(256) void k_agg1(const int* __restrict__ offsets,
                                              const int* __restrict__ elist,
                                              const float* __restrict__ dis,
                                              const float* __restrict__ ht1s,
                                              const float* __restrict__ b1,
                                              float* __restrict__ h) {
  const int wave = threadIdx.x >> 6;
  const int lane = threadIdx.x & 63;
  const int d = blockIdx.x * 4 + wave;
  const int g = lane >> 4;        // edge group 0..3
  const int fl = lane & 15;       // feature quad 0..15

  const int begin = offsets[d], end = offsets[d + 1];
  float4 acc = {0.f, 0.f, 0.f, 0.f};
  for (int j = begin + g; j < end; j += 4) {
    int s = elist[j];
    const float4 v = *(const float4*)(ht1s + (size_t)s * HID_DIM + fl * 4);
    acc.x += v.x; acc.y += v.y; acc.z += v.z; acc.w += v.w;
  }
  // reduce groups: lanes l, l+16, l+32, l+48
  acc.x += __shfl_xor(acc.x, 32); acc.y += __shfl_xor(acc.y, 32);
  acc.z += __shfl_xor(acc.z, 32); acc.w += __shfl_xor(acc.w, 32);
  acc.x += __shfl_xor(acc.x, 16); acc.y += __shfl_xor(acc.y, 16);
  acc.z += __shfl_xor(acc.z, 16); acc.w += __shfl_xor(acc.w, 16);

  if (lane < 16) {
    float dd = dis[d];
    float4 bb = *(const float4*)(b1 + lane * 4);
    float4 v;
    v.x = fmaxf(acc.x * dd + bb.x, 0.f);
    v.y = fmaxf(acc.y * dd + bb.y, 0.f);
    v.z = fmaxf(acc.z * dd + bb.z, 0.f);
    v.w = fmaxf(acc.w * dd + bb.w, 0.f);
    unsigned base = (unsigned)d * 64u + (unsigned)lane * 4u;
    unsigned o0, o1;
    threefry2x32_0_42(0u, base + 0u, o0, o1);
    v.x = ((o0 ^ o1) & 0x80000000u) ? 0.f : v.x * 2.f;
    threefry2x32_0_42(0u, base + 1u, o0, o1);
    v.y = ((o0 ^ o1) & 0x80000000u) ? 0.f : v.y * 2.f;
    threefry2x32_0_42(0u, base + 2u, o0, o1);
    v.z = ((o0 ^ o1) & 0x80000000u) ? 0.f : v.z * 2.f;
    threefry2x32_0_42(0u, base + 3u, o0, o1);
    v.w = ((o0 ^ o1) & 0x80000000u) ? 0.f : v.w * 2.f;
    *(float4*)(h + (size_t)d * HID_DIM + lane * 4) = v;
  }
}

// ---------------- GEMM2: ht2s = dis[row] * (h @ W2) ----------------
__global__ __launch_bounds__(256) void k_gemm2(const float* __restrict__ h,
                                               const float* __restrict__ Wp2,
                                               const float* __restrict__ dis,
                                               float* __restrict__ ht2s) {
  const int lane = threadIdx.x & 63;
  const int wave = threadIdx.x >> 6;
  const int cg = __builtin_amdgcn_readfirstlane(wave & 1);
  const int rb = wave >> 1;
  const int row = blockIdx.x * 128 + rb * 64 + lane;
  const bool valid = row < N_NODES;
  const float4* __restrict__ hrow =
      (const float4*)(h + (size_t)(valid ? row : 0) * HID_DIM);

  float acc[20];
#pragma unroll
  for (int i = 0; i < 20; ++i) acc[i] = 0.0f;

  for (int k0 = 0; k0 < HID_DIM; k0 += 4) {
    float4 x4 = hrow[k0 >> 2];
    const float4* __restrict__ wv = (const float4*)(Wp2 + (k0 >> 2) * 160 + cg * 80);
#pragma unroll
    for (int c = 0; c < 20; ++c) {
      float4 w = wv[c];
      acc[c] += x4.x * w.x;
      acc[c] += x4.y * w.y;
      acc[c] += x4.z * w.z;
      acc[c] += x4.w * w.w;
    }
  }
  if (valid) {
    float dr = dis[row];
    float* __restrict__ o = ht2s + (size_t)row * OUT_DIM + cg * 20;
#pragma unroll
    for (int c = 0; c < 20; ++c) o[c] = acc[c] * dr;
  }
}

// ---------------- agg2 + bias2 + log-softmax, fused ----------------
__global__ __launch_bounds__(256) void k_agg2(const int* __restrict__ offsets,
                                              const int* __restrict__ elist,
                                              const float* __restrict__ dis,
                                              const float* __restrict__ ht2s,
                                              const float* __restrict__ b2,
                                              float* __restrict__ out) {
  const int wave = threadIdx.x >> 6;
  const int lane = threadIdx.x & 63;
  const int d = blockIdx.x * 4 + wave;

  const int begin = offsets[d], end = offsets[d + 1];
  float acc = 0.f;
  if (lane < OUT_DIM) {
    for (int j = begin; j < end; ++j) {
      int s = elist[j];
      acc += ht2s[(size_t)s * OUT_DIM + lane];
    }
  }
  float v = (lane < OUT_DIM) ? acc * dis[d] + b2[lane] : -FLT_MAX;
  float m = v;
  m = fmaxf(m, __shfl_xor(m, 1));
  m = fmaxf(m, __shfl_xor(m, 2));
  m = fmaxf(m, __shfl_xor(m, 4));
  m = fmaxf(m, __shfl_xor(m, 8));
  m = fmaxf(m, __shfl_xor(m, 16));
  m = fmaxf(m, __shfl_xor(m, 32));
  float e = (lane < OUT_DIM) ? expf(v - m) : 0.f;
  e += __shfl_xor(e, 1);
  e += __shfl_xor(e, 2);
  e += __shfl_xor(e, 4);
  e += __shfl_xor(e, 8);
  e += __shfl_xor(e, 16);
  e += __shfl_xor(e, 32);
  float ls = logf(e) + m;
  if (lane < OUT_DIM) out[(size_t)d * OUT_DIM + lane] = v - ls;
}

// ---------------- launch ----------------
extern "C" void kernel_launch(void* const* d_in, const int* in_sizes, int n_in,
                              void* d_out, int out_size, void* d_ws, size_t ws_size,
                              hipStream_t stream) {
  const float* x  = (const float*)d_in[0];
  const int*   ei = (const int*)  d_in[1];
  const float* W1 = (const float*)d_in[2];
  const float* b1 = (const float*)d_in[3];
  const float* W2 = (const float*)d_in[4];
  const float* b2 = (const float*)d_in[5];
  float* out = (float*)d_out;
  float* ws  = (float*)d_ws;

  // ws layout
  float* ht   = ws;                         // 3,200,000  (ht1s, later ht2s)
  float* h    = ws + 3200000;               // 3,200,000
  float* dis  = ws + 6400000;               // 51,200
  float* Wp1  = ws + 6451200;               // 32,768
  float* Wp2  = ws + 6483968;               // 2,560
  int* ibase  = (int*)(ws + 6486528);
  int* counts  = ibase;                     // 51,200
  int* offsets = ibase + 51200;             // 51,264 (needs 50001)
  int* cursor  = ibase + 102464;            // 51,200
  int* elist   = ibase + 153664;            // 850,000
  int* bsums   = ibase + 1003664;           // 64
  int* bexcl   = ibase + 1003728;           // 64

  hipMemsetAsync(counts, 0, (size_t)N_NODES * sizeof(int), stream);

  k_count<<<3125, 256, 0, stream>>>(ei + N_EDGES, counts);
  k_scan1<<<49, 1024, 0, stream>>>(counts, offsets, bsums);
  k_scan2<<<1, 64, 0, stream>>>(bsums, bexcl);
  k_scan3<<<49, 1024, 0, stream>>>(counts, offsets, cursor, dis, elist, bexcl);
  k_fill<<<3125, 256, 0, stream>>>(ei, cursor, elist);

  k_wprep<<<128, 256, 0, stream>>>(W1, W2, Wp1, Wp2);
  k_gemm1<<<782, 256, 0, stream>>>(x, Wp1, dis, ht);
  k_agg1<<<12500, 256, 0, stream>>>(offsets, elist, dis, ht, b1, h);
  k_gemm2<<<391, 256, 0, stream>>>(h, Wp2, dis, ht);
  k_agg2<<<12500, 256, 0, stream>>>(offsets, elist, dis, ht, b2, out);
}